// Round 1
// 819.216 us; speedup vs baseline: 1.1005x; 1.1005x over previous
//
#include <hip/hip_runtime.h>
#include <stdint.h>

#define DIM   2048
#define BATCH 4
#define SEQ   4096
#define NTOK  (BATCH*SEQ)      // 16384
#define NCH   256              // cumsum chunks per sequence
#define CHUNK (SEQ/NCH)        // 16 tokens per chunk

// workspace layout (bytes)
#define XB_BYTES   ((size_t)NTOK*DIM*2)          // x in bf16
#define WB_BYTES   ((size_t)4*DIM*DIM*2)         // 4 weights in bf16
#define PW_BYTES   ((size_t)2*NTOK*DIM*2)        // w = q*sig(g), p = k*v  (bf16)
#define PART_BYTES ((size_t)BATCH*NCH*DIM*4)     // chunk partial sums, fp32

typedef __bf16 bf16x8 __attribute__((ext_vector_type(8)));
typedef float  f32x4  __attribute__((ext_vector_type(4)));

__device__ __forceinline__ unsigned short f2bf(float f) {
  unsigned int u = __float_as_uint(f);
  u += 0x7FFFu + ((u >> 16) & 1u);          // round-to-nearest-even
  return (unsigned short)(u >> 16);
}
__device__ __forceinline__ float bflo(unsigned int u){ return __uint_as_float(u << 16); }
__device__ __forceinline__ float bfhi(unsigned int u){ return __uint_as_float(u & 0xFFFF0000u); }
__device__ __forceinline__ float sigm(float x){ return 1.0f/(1.0f + __expf(-x)); }

__device__ __forceinline__ void gload16(const void* g, void* l) {
  __builtin_amdgcn_global_load_lds((const __attribute__((address_space(1))) unsigned int*)g,
                                   (__attribute__((address_space(3))) unsigned int*)l,
                                   16, 0, 0);
}

// ---------------- fp32 -> bf16 conversion (8 elems/thread) ----------------
__global__ void cvt_kernel(const float* __restrict__ src,
                           unsigned short* __restrict__ dst, int n8) {
  int i = blockIdx.x * blockDim.x + threadIdx.x;
  if (i >= n8) return;
  const float4* s4 = (const float4*)src;
  float4 a = s4[2*i], b = s4[2*i+1];
  uint4 o;
  o.x = (unsigned int)f2bf(a.x) | ((unsigned int)f2bf(a.y) << 16);
  o.y = (unsigned int)f2bf(a.z) | ((unsigned int)f2bf(a.w) << 16);
  o.z = (unsigned int)f2bf(b.x) | ((unsigned int)f2bf(b.y) << 16);
  o.w = (unsigned int)f2bf(b.z) | ((unsigned int)f2bf(b.w) << 16);
  ((uint4*)dst)[i] = o;
}

__global__ void cvt_w_kernel(const float* __restrict__ Wq, const float* __restrict__ Wk,
                             const float* __restrict__ Wv, const float* __restrict__ Wg,
                             unsigned short* __restrict__ dst) {
  const int z = blockIdx.y;
  const float* src = (z == 0) ? Wq : (z == 1) ? Wk : (z == 2) ? Wv : Wg;
  int i = blockIdx.x * blockDim.x + threadIdx.x;
  const float4* s4 = (const float4*)src;
  float4 a = s4[2*i], b = s4[2*i+1];
  uint4 o;
  o.x = (unsigned int)f2bf(a.x) | ((unsigned int)f2bf(a.y) << 16);
  o.y = (unsigned int)f2bf(a.z) | ((unsigned int)f2bf(a.w) << 16);
  o.z = (unsigned int)f2bf(b.x) | ((unsigned int)f2bf(b.y) << 16);
  o.w = (unsigned int)f2bf(b.z) | ((unsigned int)f2bf(b.w) << 16);
  ((uint4*)(dst + (size_t)z * DIM * DIM))[i] = o;
}

// ---------------- 8-phase pipelined paired GEMM (256M x 128N x 2 weights) ----
// Structure = m201 256^2 template adapted for weight pairing:
//   BK=64, 8 waves (4M x 2N), per-wave 64x64 per weight, LDS 128 KiB
//   (2 dbuf x {A 256x64, Ba 128x64, Bb 128x64}).
// Per iteration: 2 K-tiles x 4 phases; each phase = {ds_read frags,
//   stage 1 half-tile (2x global_load_lds), barrier, lgkmcnt(0),
//   setprio(1), 16 MFMA, setprio(0), barrier}.  vmcnt(6) at p4/p8 only,
//   never 0 in steady state; last iteration peeled (vmcnt(0) once).
// LDS swizzle: chunk ^= (row&7) on BOTH stage-source and read (involution).
#define BK    64
#define NKT   (DIM/BK)     // 32
#define NIT   (NKT/2)      // 16

#define A0_OFF 0           // ushort offsets within one 32768-ushort buffer
#define A1_OFF 8192
#define BA_OFF 16384
#define BB_OFF 24576

#define STG(Lb, HOFF, GP, TILE) do {                        \
    const unsigned short* _g = (GP) + (TILE) * BK;          \
    unsigned short* _l = (Lb) + (HOFF) + t * 8;             \
    gload16(_g, _l);                                        \
    gload16(_g + (size_t)64 * DIM, _l + 4096);              \
  } while (0)

#define LDA(L) do { _Pragma("unroll")                       \
    for (int i = 0; i < 4; i++) {                           \
      afr[i][0] = *(const bf16x8*)&(L)[arow[i] + sw0];      \
      afr[i][1] = *(const bf16x8*)&(L)[arow[i] + sw1]; } } while (0)

#define LDB(L, BOFF, J0) do { _Pragma("unroll")                        \
    for (int j = 0; j < 2; j++) {                                      \
      bfr[j][0] = *(const bf16x8*)&(L)[(BOFF) + brow[(J0)+j] + sw0];   \
      bfr[j][1] = *(const bf16x8*)&(L)[(BOFF) + brow[(J0)+j] + sw1]; } } while (0)

#define MM16(ACC, J0) do { _Pragma("unroll")                                     \
    for (int kk = 0; kk < 2; kk++) { _Pragma("unroll")                           \
      for (int i = 0; i < 4; i++) { _Pragma("unroll")                            \
        for (int j = 0; j < 2; j++) {                                            \
          ACC[i][(J0)+j] = __builtin_amdgcn_mfma_f32_16x16x32_bf16(              \
              afr[i][kk], bfr[j][kk], ACC[i][(J0)+j], 0, 0, 0); } } } } while (0)

#define BARR()  __builtin_amdgcn_s_barrier()
#define LGKM0() asm volatile("s_waitcnt lgkmcnt(0)" ::: "memory")
#define VMC6()  asm volatile("s_waitcnt vmcnt(6)" ::: "memory")
#define VMC0()  asm volatile("s_waitcnt vmcnt(0)" ::: "memory")

__global__ __launch_bounds__(512, 2)
void gemm_kernel(const unsigned short* __restrict__ xb,
                 const unsigned short* __restrict__ Wall,
                 const float* __restrict__ bq, const float* __restrict__ bk,
                 const float* __restrict__ bv, const float* __restrict__ bg,
                 unsigned short* __restrict__ Yw,
                 unsigned short* __restrict__ Yp) {
  __shared__ __align__(16) unsigned short lds[2][32768];   // 128 KiB

  const int t  = threadIdx.x;
  const int e0 = blockIdx.x * 128;
  const int m0 = blockIdx.y * 256;
  const int zg = blockIdx.z;                // 0: (q,g)->w   1: (k,v)->p
  const unsigned short* Wa = Wall + (size_t)(zg == 0 ? 0 : 1) * DIM * DIM;
  const unsigned short* Wb = Wall + (size_t)(zg == 0 ? 3 : 2) * DIM * DIM;

  // staging: thread t owns LDS bytes t*16 within each 16KB half (2 calls, +8KB)
  // linear LDS row = t>>3 (+64 on call 2); swizzled global source chunk:
  const int srow = t >> 3;                   // 0..63
  const int csrc = (t & 7) ^ (srow & 7);
  const unsigned short* gA0 = xb + (size_t)(m0 + srow) * DIM + csrc * 8;
  const unsigned short* gA1 = gA0 + (size_t)128 * DIM;
  const unsigned short* gBa = Wa + (size_t)(e0 + srow) * DIM + csrc * 8;
  const unsigned short* gBb = Wb + (size_t)(e0 + srow) * DIM + csrc * 8;

  unsigned short* L0 = &lds[0][0];
  unsigned short* L1 = &lds[1][0];

  // compute-side addressing
  const int lane = t & 63, wave = t >> 6;
  const int wm = wave >> 1, wn = wave & 1;   // 4M x 2N waves
  const int lr = lane & 15, lq = lane >> 4;
  const int sw0 = ((0 + lq) ^ (lr & 7)) * 8; // kk=0 swizzled chunk (ushorts)
  const int sw1 = ((4 + lq) ^ (lr & 7)) * 8; // kk=1
  int arow[4], brow[4];
  #pragma unroll
  for (int i = 0; i < 4; i++) arow[i] = (wm * 64 + i * 16 + lr) * 64;
  #pragma unroll
  for (int j = 0; j < 4; j++) brow[j] = (wn * 64 + j * 16 + lr) * 64;

  bf16x8 afr[4][2], bfr[2][2];
  f32x4 accA[4][4], accB[4][4];
  #pragma unroll
  for (int i = 0; i < 4; i++)
    #pragma unroll
    for (int j = 0; j < 4; j++) {
      accA[i][j] = (f32x4){0.f, 0.f, 0.f, 0.f};
      accB[i][j] = (f32x4){0.f, 0.f, 0.f, 0.f};
    }

  // prologue: tile0 fully -> buf0; tile1 A0,A1,Ba -> buf1 (Bb(1) staged at p1)
  STG(L0, A0_OFF, gA0, 0);
  STG(L0, A1_OFF, gA1, 0);
  STG(L0, BA_OFF, gBa, 0);
  STG(L0, BB_OFF, gBb, 0);
  STG(L1, A0_OFF, gA0, 1);
  STG(L1, A1_OFF, gA1, 1);
  STG(L1, BA_OFF, gBa, 1);
  VMC6();                                    // tile0's 8 loads landed
  BARR();

  #pragma unroll 1
  for (int it = 0; it < NIT; ++it) {
    const int T1 = 2 * it + 1, T2 = 2 * it + 2, T3 = 2 * it + 3;
    const bool nl = (it != NIT - 1);
    // ---- K-tile 2it in L0 ----
    // P1: a + ba[0..1]; stage Bb(T1)->buf1 (buf1.Bb last read prev p8)
    LDA(L0); LDB(L0, BA_OFF, 0);
    STG(L1, BB_OFF, gBb, T1);
    BARR(); LGKM0();
    __builtin_amdgcn_s_setprio(1); MM16(accA, 0); __builtin_amdgcn_s_setprio(0);
    BARR();
    // P2: bb[0..1]; stage A0(T2)->buf0 (A fully reg-loaded in P1)
    LDB(L0, BB_OFF, 0);
    if (nl) STG(L0, A0_OFF, gA0, T2);
    BARR(); LGKM0();
    __builtin_amdgcn_s_setprio(1); MM16(accB, 0); __builtin_amdgcn_s_setprio(0);
    BARR();
    // P3: ba[2..3]; stage A1(T2)->buf0
    LDB(L0, BA_OFF, 2);
    if (nl) STG(L0, A1_OFF, gA1, T2);
    BARR(); LGKM0();
    __builtin_amdgcn_s_setprio(1); MM16(accA, 2); __builtin_amdgcn_s_setprio(0);
    BARR();
    // P4: bb[2..3]; stage Ba(T2)->buf0 (Ba last read in P3); counted wait
    LDB(L0, BB_OFF, 2);
    if (nl) { STG(L0, BA_OFF, gBa, T2); VMC6(); } else { VMC0(); }
    BARR(); LGKM0();
    __builtin_amdgcn_s_setprio(1); MM16(accB, 2); __builtin_amdgcn_s_setprio(0);
    BARR();
    // ---- K-tile 2it+1 in L1 ----
    // P5: a + ba[0..1]; stage Bb(T2)->buf0 (buf0.Bb last read in P4)
    LDA(L1); LDB(L1, BA_OFF, 0);
    if (nl) STG(L0, BB_OFF, gBb, T2);
    BARR(); LGKM0();
    __builtin_amdgcn_s_setprio(1); MM16(accA, 0); __builtin_amdgcn_s_setprio(0);
    BARR();
    // P6: bb[0..1]; stage A0(T3)->buf1
    LDB(L1, BB_OFF, 0);
    if (nl) STG(L1, A0_OFF, gA0, T3);
    BARR(); LGKM0();
    __builtin_amdgcn_s_setprio(1); MM16(accB, 0); __builtin_amdgcn_s_setprio(0);
    BARR();
    // P7: ba[2..3]; stage A1(T3)->buf1
    LDB(L1, BA_OFF, 2);
    if (nl) STG(L1, A1_OFF, gA1, T3);
    BARR(); LGKM0();
    __builtin_amdgcn_s_setprio(1); MM16(accA, 2); __builtin_amdgcn_s_setprio(0);
    BARR();
    // P8: bb[2..3]; stage Ba(T3)->buf1; counted wait gates T2 for next P1
    LDB(L1, BB_OFF, 2);
    if (nl) { STG(L1, BA_OFF, gBa, T3); VMC6(); }
    BARR(); LGKM0();
    __builtin_amdgcn_s_setprio(1); MM16(accB, 2); __builtin_amdgcn_s_setprio(0);
    BARR();
  }

  // epilogue: C/D layout col=lane&15 (=> e), row=(lane>>4)*4+reg (=> token m)
  const float* biasA = (zg == 0) ? bq : bk;
  const float* biasB = (zg == 0) ? bg : bv;
  unsigned short* Y = (zg == 0) ? Yw : Yp;
  #pragma unroll
  for (int j = 0; j < 4; j++) {
    const int e = e0 + wn * 64 + j * 16 + lr;
    const float bA = biasA[e];
    const float bB = biasB[e];
    #pragma unroll
    for (int i = 0; i < 4; i++) {
      const int mb = m0 + wm * 64 + i * 16 + lq * 4;
      #pragma unroll
      for (int r = 0; r < 4; r++) {
        const float vA = accA[i][j][r] + bA;
        const float vB = accB[i][j][r] + bB;
        const float val = (zg == 0) ? (vA * sigm(vB)) : (vA * vB);
        Y[(size_t)(mb + r) * DIM + e] = f2bf(val);
      }
    }
  }
}

// ---------------- phase 1: per-chunk partial sums of p ----------------
// grid (1, NCH, BATCH), block 256; 8 channels per thread (16B/lane loads)
__global__ void chunk_sum_kernel(const unsigned short* __restrict__ Yp,
                                 float* __restrict__ partial) {
  const int d8 = threadIdx.x;               // uint4 index within row (0..255)
  const int c = blockIdx.y, b = blockIdx.z;
  const size_t base = (size_t)(b*SEQ + c*CHUNK) * (DIM/8) + d8;
  const uint4* pp = (const uint4*)Yp + base;
  float s[8] = {0.f,0.f,0.f,0.f,0.f,0.f,0.f,0.f};
  #pragma unroll 4
  for (int i = 0; i < CHUNK; i++) {
    uint4 pu = pp[(size_t)i*(DIM/8)];
    s[0] += bflo(pu.x);  s[1] += bfhi(pu.x);
    s[2] += bflo(pu.y);  s[3] += bfhi(pu.y);
    s[4] += bflo(pu.z);  s[5] += bfhi(pu.z);
    s[6] += bflo(pu.w);  s[7] += bfhi(pu.w);
  }
  float4* po = (float4*)(partial + (size_t)(b*NCH + c)*DIM + d8*8);
  po[0] = make_float4(s[0], s[1], s[2], s[3]);
  po[1] = make_float4(s[4], s[5], s[6], s[7]);
}

// ---------------- phase 2: exclusive scan along chunks (wave shfl scan) ----------------
// one wave per (b,d) channel; 4 chunk-values per lane (NCH=256)
__global__ void scan_kernel(float* __restrict__ partial) {
  const int wid  = (blockIdx.x * blockDim.x + threadIdx.x) >> 6;  // 0..BATCH*DIM-1
  const int lane = threadIdx.x & 63;
  const int b = wid >> 11;           // / DIM
  const int d = wid & (DIM - 1);
  float* base = partial + (size_t)b * NCH * DIM + d;
  float v[4];
  #pragma unroll
  for (int k = 0; k < 4; k++) v[k] = base[(size_t)(lane*4 + k) * DIM];
  float sum = v[0] + v[1] + v[2] + v[3];
  float inc = sum;
  #pragma unroll
  for (int off = 1; off < 64; off <<= 1) {
    float n = __shfl_up(inc, off, 64);
    if (lane >= off) inc += n;
  }
  float run = inc - sum;             // exclusive prefix for this lane's group
  #pragma unroll
  for (int k = 0; k < 4; k++) {
    base[(size_t)(lane*4 + k) * DIM] = run;
    run += v[k];
  }
}

// ---------------- phase 3: cumsum within chunk + output = w * state ----------------
// grid (1, NCH, BATCH), block 256; 8 channels per thread
__global__ void final_kernel(const unsigned short* __restrict__ Yw,
                             const unsigned short* __restrict__ Yp,
                             const float* __restrict__ partial,
                             float* __restrict__ out) {
  const int d8 = threadIdx.x;
  const int c = blockIdx.y, b = blockIdx.z;
  const size_t base = (size_t)(b*SEQ + c*CHUNK) * (DIM/8) + d8;
  const float4* pst = (const float4*)(partial + (size_t)(b*NCH + c)*DIM + d8*8);
  float4 st0 = pst[0], st1 = pst[1];
  float s[8] = {st0.x, st0.y, st0.z, st0.w, st1.x, st1.y, st1.z, st1.w};
  const uint4* pw = (const uint4*)Yw + base;
  const uint4* pp = (const uint4*)Yp + base;
  float4* po = (float4*)out + base*2;
  #pragma unroll 2
  for (int i = 0; i < CHUNK; i++) {
    uint4 pu = pp[(size_t)i*(DIM/8)];
    uint4 wu = pw[(size_t)i*(DIM/8)];
    s[0] += bflo(pu.x);  s[1] += bfhi(pu.x);
    s[2] += bflo(pu.y);  s[3] += bfhi(pu.y);
    s[4] += bflo(pu.z);  s[5] += bfhi(pu.z);
    s[6] += bflo(pu.w);  s[7] += bfhi(pu.w);
    float4 o0, o1;
    o0.x = bflo(wu.x)*s[0];  o0.y = bfhi(wu.x)*s[1];
    o0.z = bflo(wu.y)*s[2];  o0.w = bfhi(wu.y)*s[3];
    o1.x = bflo(wu.z)*s[4];  o1.y = bfhi(wu.z)*s[5];
    o1.z = bflo(wu.w)*s[6];  o1.w = bfhi(wu.w)*s[7];
    po[(size_t)i*(DIM/4)]     = o0;
    po[(size_t)i*(DIM/4) + 1] = o1;
  }
}

extern "C" void kernel_launch(void* const* d_in, const int* in_sizes, int n_in,
                              void* d_out, int out_size, void* d_ws, size_t ws_size,
                              hipStream_t stream) {
  const float* x  = (const float*)d_in[0];
  const float* Wq = (const float*)d_in[1];
  const float* bq = (const float*)d_in[2];
  const float* Wk = (const float*)d_in[3];
  const float* bk = (const float*)d_in[4];
  const float* Wv = (const float*)d_in[5];
  const float* bv = (const float*)d_in[6];
  const float* Wg = (const float*)d_in[7];
  const float* bg = (const float*)d_in[8];
  float* out = (float*)d_out;

  char* ws = (char*)d_ws;
  unsigned short* xb      = (unsigned short*)(ws);
  unsigned short* Wall    = (unsigned short*)(ws + XB_BYTES);
  unsigned short* Yw      = (unsigned short*)(ws + XB_BYTES + WB_BYTES);
  unsigned short* Yp      = Yw + (size_t)NTOK * DIM;
  float*          partial = (float*)(ws + XB_BYTES + WB_BYTES + PW_BYTES);

  // 1) cast inputs to bf16
  {
    int n8 = NTOK * DIM / 8;
    cvt_kernel<<<n8 / 256, 256, 0, stream>>>(x, xb, n8);
    int w8 = DIM * DIM / 8;
    cvt_w_kernel<<<dim3(w8 / 256, 4), 256, 0, stream>>>(Wq, Wk, Wv, Wg, Wall);
  }

  // 2) paired GEMMs with fused products: Yw = q*sig(g), Yp = k*v
  gemm_kernel<<<dim3(DIM/128, NTOK/256, 2), 512, 0, stream>>>(
      xb, Wall, bq, bk, bv, bg, Yw, Yp);

  // 3) chunked cumsum of p along seq, then out = w * state
  chunk_sum_kernel<<<dim3(1, NCH, BATCH), 256, 0, stream>>>(Yp, partial);
  scan_kernel<<<(BATCH*DIM*64)/256, 256, 0, stream>>>(partial);
  final_kernel<<<dim3(1, NCH, BATCH), 256, 0, stream>>>(Yw, Yp, partial, out);
}